// Round 1
// baseline (6198.811 us; speedup 1.0000x reference)
//
#include <hip/hip_runtime.h>
#include <math.h>

#define B 64
#define N 196
#define E 2048
#define D 512
#define AA 512
#define EM 512
#define V 10000
#define TSTEPS 20

__device__ __forceinline__ float sigmoidf_(float x) { return 1.0f / (1.0f + expf(-x)); }

// ---------------- mean over N: mean_enc[b,e] ----------------
__global__ __launch_bounds__(256) void k_mean(const float* __restrict__ feat,
                                              float* __restrict__ mean_enc) {
    int i = blockIdx.x * 256 + threadIdx.x;      // b*E + e, total B*E = 131072
    int b = i >> 11;                             // /E
    int e = i & (E - 1);
    const float* p = feat + (size_t)b * N * E + e;
    float s = 0.f;
    for (int n = 0; n < N; ++n) s += p[(size_t)n * E];
    mean_enc[i] = s * (1.0f / (float)N);
}

// ---------------- h,c init: [B,D] = mean_enc @ W + b ----------------
__global__ __launch_bounds__(256) void k_init_hc(const float* __restrict__ me,
                                                 const float* __restrict__ Wh, const float* __restrict__ bh,
                                                 const float* __restrict__ Wc, const float* __restrict__ bc,
                                                 float* __restrict__ h, float* __restrict__ c) {
    int i = blockIdx.x * 256 + threadIdx.x;      // b*D + d, total B*D = 32768
    int b = i >> 9;                              // /D
    int d = i & (D - 1);
    const float* m = me + (size_t)b * E;
    float ha = bh[d], ca = bc[d];
    for (int e = 0; e < E; ++e) {
        float mv = m[e];
        ha += mv * Wh[(size_t)e * D + d];
        ca += mv * Wc[(size_t)e * D + d];
    }
    h[i] = ha; c[i] = ca;
}

// ---------------- inp = embedding[1] ----------------
__global__ __launch_bounds__(256) void k_init_inp(const float* __restrict__ emb,
                                                  float* __restrict__ inp) {
    int i = blockIdx.x * 256 + threadIdx.x;      // b*EM + k, total 32768
    int k = i & (EM - 1);
    inp[i] = emb[EM + k];                        // row 1
}

// ---------------- att1 = enc[M=12544,K=2048] @ W_enc_att[K,512] ----------------
// 64x64 tile, BK=16, 256 threads, 4x4 microtile
__global__ __launch_bounds__(256) void k_gemm_att1(const float* __restrict__ Am,
                                                   const float* __restrict__ Bm,
                                                   float* __restrict__ Cm) {
    const int M = B * N, K = E, Nn = AA;
    __shared__ float As[64][17];
    __shared__ float Bs[16][64];
    int t = threadIdx.x;
    int tx = t & 15, ty = t >> 4;
    int row0 = blockIdx.x * 64;
    int col0 = blockIdx.y * 64;
    int arow = t >> 2, ak4 = (t & 3) * 4;        // A tile: 64 rows x 16 k (float4 per thread)
    int bk = t >> 4, bc4 = (t & 15) * 4;         // B tile: 16 k x 64 cols
    float acc[4][4] = {};
    for (int k0 = 0; k0 < K; k0 += 16) {
        float4 av = *(const float4*)&Am[(size_t)(row0 + arow) * K + k0 + ak4];
        As[arow][ak4 + 0] = av.x; As[arow][ak4 + 1] = av.y;
        As[arow][ak4 + 2] = av.z; As[arow][ak4 + 3] = av.w;
        float4 bv = *(const float4*)&Bm[(size_t)(k0 + bk) * Nn + col0 + bc4];
        *(float4*)&Bs[bk][bc4] = bv;
        __syncthreads();
#pragma unroll
        for (int kk = 0; kk < 16; ++kk) {
            float a0 = As[ty * 4 + 0][kk], a1 = As[ty * 4 + 1][kk];
            float a2 = As[ty * 4 + 2][kk], a3 = As[ty * 4 + 3][kk];
            float4 bb = *(const float4*)&Bs[kk][tx * 4];
            acc[0][0] += a0 * bb.x; acc[0][1] += a0 * bb.y; acc[0][2] += a0 * bb.z; acc[0][3] += a0 * bb.w;
            acc[1][0] += a1 * bb.x; acc[1][1] += a1 * bb.y; acc[1][2] += a1 * bb.z; acc[1][3] += a1 * bb.w;
            acc[2][0] += a2 * bb.x; acc[2][1] += a2 * bb.y; acc[2][2] += a2 * bb.z; acc[2][3] += a2 * bb.w;
            acc[3][0] += a3 * bb.x; acc[3][1] += a3 * bb.y; acc[3][2] += a3 * bb.z; acc[3][3] += a3 * bb.w;
        }
        __syncthreads();
    }
#pragma unroll
    for (int i = 0; i < 4; ++i) {
#pragma unroll
        for (int j = 0; j < 4; ++j)
            Cm[(size_t)(row0 + ty * 4 + i) * Nn + col0 + tx * 4 + j] = acc[i][j];
    }
}

// ---------------- att2 = h @ W_dec_att  [B,A] ----------------
__global__ __launch_bounds__(256) void k_att2(const float* __restrict__ h,
                                              const float* __restrict__ Wda,
                                              float* __restrict__ att2) {
    int i = blockIdx.x * 256 + threadIdx.x;      // b*A + a, total 32768
    int b = i >> 9, a = i & (AA - 1);
    const float* hp = h + (size_t)b * D;
    float s = 0.f;
    for (int d = 0; d < D; ++d) s += hp[d] * Wda[(size_t)d * AA + a];
    att2[i] = s;
}

// ---------------- scores[bn] = sum_a relu(att1+att2)*w_full — wave per bn ----------------
__global__ __launch_bounds__(256) void k_scores(const float* __restrict__ att1,
                                                const float* __restrict__ att2,
                                                const float* __restrict__ wfull,
                                                float* __restrict__ scores) {
    int wave = threadIdx.x >> 6, lane = threadIdx.x & 63;
    int bn = blockIdx.x * 4 + wave;              // 12544 total
    int b = bn / N;
    const float* a1 = att1 + (size_t)bn * AA;
    const float* a2 = att2 + (size_t)b * AA;
    float s = 0.f;
#pragma unroll
    for (int i = 0; i < AA / 64; ++i) {
        int a = lane + i * 64;
        float v = a1[a] + a2[a];
        s += fmaxf(v, 0.f) * wfull[a];
    }
    for (int off = 32; off; off >>= 1) s += __shfl_down(s, off);
    if (lane == 0) scores[bn] = s;
}

// ---------------- softmax over N per b ----------------
__global__ __launch_bounds__(256) void k_softmax(const float* __restrict__ scores,
                                                 float* __restrict__ alpha) {
    __shared__ float sm[256];
    int b = blockIdx.x, t = threadIdx.x;
    float v = (t < N) ? scores[b * N + t] : -INFINITY;
    sm[t] = v; __syncthreads();
    for (int s = 128; s; s >>= 1) { if (t < s) sm[t] = fmaxf(sm[t], sm[t + s]); __syncthreads(); }
    float mx = sm[0]; __syncthreads();
    float e = (t < N) ? expf(v - mx) : 0.f;
    sm[t] = e; __syncthreads();
    for (int s = 128; s; s >>= 1) { if (t < s) sm[t] += sm[t + s]; __syncthreads(); }
    float inv = 1.0f / sm[0];
    if (t < N) alpha[b * N + t] = e * inv;
}

// ---------------- awe[b,e] = gate * sum_n alpha*enc ----------------
__global__ __launch_bounds__(256) void k_awe_gate(const float* __restrict__ alpha,
                                                  const float* __restrict__ feat,
                                                  const float* __restrict__ h,
                                                  const float* __restrict__ Wfb,
                                                  const float* __restrict__ bfb,
                                                  float* __restrict__ awe) {
    int i = blockIdx.x * 256 + threadIdx.x;      // b*E + e, total 131072
    int b = i >> 11, e = i & (E - 1);
    const float* al = alpha + b * N;
    const float* ep = feat + (size_t)b * N * E + e;
    float s = 0.f;
    for (int n = 0; n < N; ++n) s += al[n] * ep[(size_t)n * E];
    const float* hp = h + (size_t)b * D;
    float g = bfb[e];
    for (int d = 0; d < D; ++d) g += hp[d] * Wfb[(size_t)d * E + e];
    awe[i] = s * sigmoidf_(g);
}

// ---------------- z = [inp,awe] @ W_ih + h @ W_hh + b_lstm  [B,4D] ----------------
__global__ __launch_bounds__(256) void k_z(const float* __restrict__ inp,
                                           const float* __restrict__ awe,
                                           const float* __restrict__ h,
                                           const float* __restrict__ Wih,
                                           const float* __restrict__ Whh,
                                           const float* __restrict__ blstm,
                                           float* __restrict__ z) {
    int i = blockIdx.x * 256 + threadIdx.x;      // b*2048 + j, total 131072
    int b = i >> 11, j = i & (4 * D - 1);
    float s = blstm[j];
    const float* xi = inp + (size_t)b * EM;
    for (int k = 0; k < EM; ++k) s += xi[k] * Wih[(size_t)k * (4 * D) + j];
    const float* xa = awe + (size_t)b * E;
    for (int k = 0; k < E; ++k) s += xa[k] * Wih[(size_t)(EM + k) * (4 * D) + j];
    const float* hp = h + (size_t)b * D;
    for (int d = 0; d < D; ++d) s += hp[d] * Whh[(size_t)d * (4 * D) + j];
    z[i] = s;
}

// ---------------- LSTM elementwise: updates h,c in place ----------------
__global__ __launch_bounds__(256) void k_lstm(const float* __restrict__ z,
                                              float* __restrict__ c,
                                              float* __restrict__ h) {
    int i = blockIdx.x * 256 + threadIdx.x;      // b*D + d, total 32768
    int b = i >> 9, d = i & (D - 1);
    const float* zb = z + (size_t)b * (4 * D);
    float iv = sigmoidf_(zb[d]);
    float fv = sigmoidf_(zb[D + d]);
    float gv = tanhf(zb[2 * D + d]);
    float ov = sigmoidf_(zb[3 * D + d]);
    float cn = fv * c[i] + iv * gv;
    c[i] = cn;
    h[i] = ov * tanhf(cn);
}

// ---------------- preds = h @ W_fc + b_fc  [B,V] ----------------
__global__ __launch_bounds__(256) void k_preds(const float* __restrict__ h,
                                               const float* __restrict__ Wfc,
                                               const float* __restrict__ bfc,
                                               float* __restrict__ preds) {
    int v = blockIdx.x * 256 + threadIdx.x;
    int b = blockIdx.y;
    if (v >= V) return;
    const float* hp = h + (size_t)b * D;
    float s = bfc[v];
    for (int d = 0; d < D; ++d) s += hp[d] * Wfc[(size_t)d * V + v];
    preds[(size_t)b * V + v] = s;
}

// ---------------- argmax over V, write token, gather next inp ----------------
__global__ __launch_bounds__(256) void k_argmax(const float* __restrict__ preds,
                                                const float* __restrict__ emb,
                                                float* __restrict__ inp,
                                                int* __restrict__ out,
                                                int step) {
    __shared__ float vals[256];
    __shared__ int idxs[256];
    __shared__ int pid_sh;
    int b = blockIdx.x, t = threadIdx.x;
    const float* p = preds + (size_t)b * V;
    float best = -INFINITY; int bi = 0;
    for (int v = t; v < V; v += 256) {
        float pv = p[v];
        if (pv > best) { best = pv; bi = v; }    // ascending scan: strict > keeps first max
    }
    vals[t] = best; idxs[t] = bi; __syncthreads();
    for (int s = 128; s; s >>= 1) {
        if (t < s) {
            float ov = vals[t + s]; int oi = idxs[t + s];
            if (ov > vals[t] || (ov == vals[t] && oi < idxs[t])) { vals[t] = ov; idxs[t] = oi; }
        }
        __syncthreads();
    }
    if (t == 0) { pid_sh = idxs[0]; out[b * TSTEPS + step] = idxs[0]; }
    __syncthreads();
    int pid = pid_sh;
    for (int k = t; k < EM; k += 256) inp[(size_t)b * EM + k] = emb[(size_t)pid * EM + k];
}

extern "C" void kernel_launch(void* const* d_in, const int* in_sizes, int n_in,
                              void* d_out, int out_size, void* d_ws, size_t ws_size,
                              hipStream_t stream) {
    const float* feat   = (const float*)d_in[0];
    const float* emb    = (const float*)d_in[1];
    const float* Wea    = (const float*)d_in[2];
    const float* Wda    = (const float*)d_in[3];
    const float* wfull  = (const float*)d_in[4];
    const float* Wih_   = (const float*)d_in[5];
    const float* bih    = (const float*)d_in[6];
    const float* Wic    = (const float*)d_in[7];
    const float* bic    = (const float*)d_in[8];
    const float* Wfb    = (const float*)d_in[9];
    const float* bfb    = (const float*)d_in[10];
    const float* Wih    = (const float*)d_in[11];
    const float* Whh    = (const float*)d_in[12];
    const float* blstm  = (const float*)d_in[13];
    const float* Wfc    = (const float*)d_in[14];
    const float* bfc    = (const float*)d_in[15];
    int* out = (int*)d_out;

    float* ws = (float*)d_ws;
    float* att1     = ws;                        // B*N*A   = 6422528
    float* mean_enc = att1 + (size_t)B * N * AA; // B*E     = 131072
    float* h        = mean_enc + (size_t)B * E;  // B*D
    float* c        = h + (size_t)B * D;
    float* att2     = c + (size_t)B * D;         // B*A
    float* scores   = att2 + (size_t)B * AA;     // B*N
    float* alpha    = scores + (size_t)B * N;
    float* awe      = alpha + (size_t)B * N;     // B*E
    float* z        = awe + (size_t)B * E;       // B*4D
    float* preds    = z + (size_t)B * 4 * D;     // B*V
    float* inp      = preds + (size_t)B * V;     // B*EM

    k_mean<<<(B * E) / 256, 256, 0, stream>>>(feat, mean_enc);
    k_init_hc<<<(B * D) / 256, 256, 0, stream>>>(mean_enc, Wih_, bih, Wic, bic, h, c);
    k_init_inp<<<(B * EM) / 256, 256, 0, stream>>>(emb, inp);
    k_gemm_att1<<<dim3((B * N) / 64, AA / 64), 256, 0, stream>>>(feat, Wea, att1);

    for (int t = 0; t < TSTEPS; ++t) {
        k_att2<<<(B * AA) / 256, 256, 0, stream>>>(h, Wda, att2);
        k_scores<<<(B * N) / 4, 256, 0, stream>>>(att1, att2, wfull, scores);
        k_softmax<<<B, 256, 0, stream>>>(scores, alpha);
        k_awe_gate<<<(B * E) / 256, 256, 0, stream>>>(alpha, feat, h, Wfb, bfb, awe);
        k_z<<<(B * 4 * D) / 256, 256, 0, stream>>>(inp, awe, h, Wih, Whh, blstm, z);
        k_lstm<<<(B * D) / 256, 256, 0, stream>>>(z, c, h);
        k_preds<<<dim3((V + 255) / 256, B), 256, 0, stream>>>(h, Wfc, bfc, preds);
        k_argmax<<<B, 256, 0, stream>>>(preds, emb, inp, out, t);
    }
}

// Round 3
// 4400.826 us; speedup vs baseline: 1.4086x; 1.4086x over previous
//
#include <hip/hip_runtime.h>
#include <math.h>

#define B 64
#define N 196
#define E 2048
#define D 512
#define AA 512
#define EM 512
#define V 10000
#define TSTEPS 20
#define XC 3072          // xcat: [inp(512) | awe(2048) | h(512)] contiguous
#define HOFF 2560        // h slot offset in xcat
#define AGW 2560         // ag row: [att2(512) | gate(2048)]
#define ZS1 8            // split-K slices for W_ih (K=2560 -> 320 each)
#define ZS2 4            // split-K slices for W_hh (K=512 -> 128 each)

__device__ __forceinline__ float sigmoidf_(float x) { return 1.0f / (1.0f + expf(-x)); }

// ---------------- mean over N ----------------
__global__ __launch_bounds__(256) void k_mean(const float* __restrict__ feat,
                                              float* __restrict__ mean_enc) {
    int i = blockIdx.x * 256 + threadIdx.x;
    int b = i >> 11, e = i & (E - 1);
    const float* p = feat + (size_t)b * N * E + e;
    float s = 0.f;
    for (int n = 0; n < N; ++n) s += p[(size_t)n * E];
    mean_enc[i] = s * (1.0f / (float)N);
}

// ---------------- h,c init; h written into xcat h-slot ----------------
__global__ __launch_bounds__(256) void k_init_hc(const float* __restrict__ me,
                                                 const float* __restrict__ Wh, const float* __restrict__ bh,
                                                 const float* __restrict__ Wc, const float* __restrict__ bc,
                                                 float* __restrict__ xcat, float* __restrict__ c) {
    int i = blockIdx.x * 256 + threadIdx.x;
    int b = i >> 9, d = i & (D - 1);
    const float* m = me + (size_t)b * E;
    float ha = bh[d], ca = bc[d];
    for (int e = 0; e < E; ++e) {
        float mv = m[e];
        ha += mv * Wh[(size_t)e * D + d];
        ca += mv * Wc[(size_t)e * D + d];
    }
    xcat[(size_t)b * XC + HOFF + d] = ha;
    c[i] = ca;
}

// ---------------- inp = embedding[1] into xcat ----------------
__global__ __launch_bounds__(256) void k_init_inp(const float* __restrict__ emb,
                                                  float* __restrict__ xcat) {
    int i = blockIdx.x * 256 + threadIdx.x;   // 32768
    int b = i >> 9, k = i & (EM - 1);
    xcat[(size_t)b * XC + k] = emb[EM + k];
}

// ---------------- att1 = enc @ W_enc_att : 128x64 tile, BK=16, 8x4 micro ----------------
__global__ __launch_bounds__(256) void k_gemm_att1(const float* __restrict__ Am,
                                                   const float* __restrict__ Bm,
                                                   float* __restrict__ Cm) {
    __shared__ float As[16][128];   // transposed [k][m]
    __shared__ float Bs[16][64];
    int t = threadIdx.x;
    int row0 = blockIdx.x * 128, col0 = blockIdx.y * 64;
    int lrow = t >> 1, lk8 = (t & 1) * 8;
    int bk = t >> 4, bc4 = (t & 15) * 4;
    int tyn = t >> 4, txn = t & 15;
    float acc[8][4] = {};
    for (int k0 = 0; k0 < E; k0 += 16) {
        const float* ap = &Am[(size_t)(row0 + lrow) * E + k0 + lk8];
        float4 a0 = *(const float4*)ap;
        float4 a1 = *(const float4*)(ap + 4);
        As[lk8 + 0][lrow] = a0.x; As[lk8 + 1][lrow] = a0.y;
        As[lk8 + 2][lrow] = a0.z; As[lk8 + 3][lrow] = a0.w;
        As[lk8 + 4][lrow] = a1.x; As[lk8 + 5][lrow] = a1.y;
        As[lk8 + 6][lrow] = a1.z; As[lk8 + 7][lrow] = a1.w;
        *(float4*)&Bs[bk][bc4] = *(const float4*)&Bm[(size_t)(k0 + bk) * AA + col0 + bc4];
        __syncthreads();
#pragma unroll
        for (int kk = 0; kk < 16; ++kk) {
            float4 am0 = *(const float4*)&As[kk][tyn * 4];
            float4 am1 = *(const float4*)&As[kk][64 + tyn * 4];
            float4 bb  = *(const float4*)&Bs[kk][txn * 4];
#define FMA4(r, a) acc[r][0] += (a) * bb.x; acc[r][1] += (a) * bb.y; acc[r][2] += (a) * bb.z; acc[r][3] += (a) * bb.w;
            FMA4(0, am0.x) FMA4(1, am0.y) FMA4(2, am0.z) FMA4(3, am0.w)
            FMA4(4, am1.x) FMA4(5, am1.y) FMA4(6, am1.z) FMA4(7, am1.w)
#undef FMA4
        }
        __syncthreads();
    }
#pragma unroll
    for (int i = 0; i < 8; ++i) {
        int row = row0 + ((i < 4) ? (tyn * 4 + i) : (64 + tyn * 4 + i - 4));
        float4 r;
        r.x = acc[i][0]; r.y = acc[i][1]; r.z = acc[i][2]; r.w = acc[i][3];
        *(float4*)&Cm[(size_t)row * AA + col0 + txn * 4] = r;
    }
}

// ---------------- generic M=64 GEMM: C[slice] = A[64,K] @ W[K,Nn] (+bias) ----------------
template<int GUARD>
__global__ __launch_bounds__(256) void k_gemm64(const float* __restrict__ A, int lda,
                                                const float* __restrict__ W, int ldw,
                                                float* __restrict__ C, int ldc, size_t cSliceStride,
                                                const float* __restrict__ bias,
                                                int Nn, int kspan) {
    __shared__ float As[16][68];   // transposed [k][m], padded
    __shared__ float Bs[16][64];
    int t = threadIdx.x;
    int n0 = blockIdx.x * 64;
    int kbeg = blockIdx.y * kspan, kend = kbeg + kspan;
    C += (size_t)blockIdx.y * cSliceStride;
    int tx = t & 15, ty = t >> 4;
    int arow = t >> 2, ak4 = (t & 3) * 4;
    int bk = t >> 4, bc4 = (t & 15) * 4;
    float acc[4][4] = {};
    for (int k0 = kbeg; k0 < kend; k0 += 16) {
        float4 av = *(const float4*)&A[(size_t)arow * lda + k0 + ak4];
        As[ak4 + 0][arow] = av.x; As[ak4 + 1][arow] = av.y;
        As[ak4 + 2][arow] = av.z; As[ak4 + 3][arow] = av.w;
        if (GUARD) {
            int n = n0 + bc4;
            const float* wp = &W[(size_t)(k0 + bk) * ldw];
            float4 bv;
            if (n + 3 < Nn) bv = *(const float4*)&wp[n];
            else {
                bv.x = (n     < Nn) ? wp[n]     : 0.f;
                bv.y = (n + 1 < Nn) ? wp[n + 1] : 0.f;
                bv.z = (n + 2 < Nn) ? wp[n + 2] : 0.f;
                bv.w = (n + 3 < Nn) ? wp[n + 3] : 0.f;
            }
            *(float4*)&Bs[bk][bc4] = bv;
        } else {
            *(float4*)&Bs[bk][bc4] = *(const float4*)&W[(size_t)(k0 + bk) * ldw + n0 + bc4];
        }
        __syncthreads();
#pragma unroll
        for (int kk = 0; kk < 16; ++kk) {
            float4 a4 = *(const float4*)&As[kk][ty * 4];
            float4 b4 = *(const float4*)&Bs[kk][tx * 4];
            acc[0][0] += a4.x * b4.x; acc[0][1] += a4.x * b4.y; acc[0][2] += a4.x * b4.z; acc[0][3] += a4.x * b4.w;
            acc[1][0] += a4.y * b4.x; acc[1][1] += a4.y * b4.y; acc[1][2] += a4.y * b4.z; acc[1][3] += a4.y * b4.w;
            acc[2][0] += a4.z * b4.x; acc[2][1] += a4.z * b4.y; acc[2][2] += a4.z * b4.z; acc[2][3] += a4.z * b4.w;
            acc[3][0] += a4.w * b4.x; acc[3][1] += a4.w * b4.y; acc[3][2] += a4.w * b4.z; acc[3][3] += a4.w * b4.w;
        }
        __syncthreads();
    }
#pragma unroll
    for (int i = 0; i < 4; ++i) {
        int row = ty * 4 + i;
        float* cp = &C[(size_t)row * ldc];
#pragma unroll
        for (int j = 0; j < 4; ++j) {
            int col = n0 + tx * 4 + j;
            if (!GUARD || col < Nn) {
                float v = acc[i][j];
                if (bias) v += bias[col];
                cp[col] = v;
            }
        }
    }
}

// ---------------- fused scores + softmax, block per b ----------------
__global__ __launch_bounds__(256) void k_scores_softmax(const float* __restrict__ att1,
                                                        const float* __restrict__ ag,
                                                        const float* __restrict__ wfull,
                                                        float* __restrict__ alpha) {
    __shared__ float a2s[AA], wfs[AA], sc[N], red[256];
    int b = blockIdx.x, t = threadIdx.x;
    a2s[t] = ag[(size_t)b * AGW + t];
    a2s[t + 256] = ag[(size_t)b * AGW + t + 256];
    wfs[t] = wfull[t]; wfs[t + 256] = wfull[t + 256];
    __syncthreads();
    int wave = t >> 6, lane = t & 63;
    for (int n = wave; n < N; n += 4) {
        const float* a1 = att1 + ((size_t)b * N + n) * AA;
        float s = 0.f;
#pragma unroll
        for (int i = 0; i < AA / 64; ++i) {
            int a = lane + i * 64;
            s += fmaxf(a1[a] + a2s[a], 0.f) * wfs[a];
        }
        for (int off = 32; off; off >>= 1) s += __shfl_down(s, off);
        if (lane == 0) sc[n] = s;
    }
    __syncthreads();
    float v = (t < N) ? sc[t] : -INFINITY;
    red[t] = v; __syncthreads();
    for (int s = 128; s; s >>= 1) { if (t < s) red[t] = fmaxf(red[t], red[t + s]); __syncthreads(); }
    float mx = red[0]; __syncthreads();
    float e = (t < N) ? expf(v - mx) : 0.f;
    red[t] = e; __syncthreads();
    for (int s = 128; s; s >>= 1) { if (t < s) red[t] += red[t + s]; __syncthreads(); }
    float inv = 1.0f / red[0];
    if (t < N) alpha[b * N + t] = e * inv;
}

// ---------------- awe (+gate) -> xcat awe-slot; grid (4 e-chunks, 64 b) ----------------
__global__ __launch_bounds__(256) void k_awe(const float* __restrict__ alpha,
                                             const float* __restrict__ feat,
                                             const float* __restrict__ ag,
                                             float* __restrict__ xcat) {
    __shared__ float al[N];
    int b = blockIdx.y, chunk = blockIdx.x, t = threadIdx.x;
    if (t < N) al[t] = alpha[b * N + t];
    __syncthreads();
    int e0 = chunk * 512;
    float s0 = 0.f, s1 = 0.f;
    const float* f = feat + (size_t)b * N * E + e0 + t;
    for (int n = 0; n < N; ++n) { float a = al[n]; s0 += a * f[0]; s1 += a * f[256]; f += E; }
    int e = e0 + t;
    float g0 = ag[(size_t)b * AGW + AA + e];
    float g1 = ag[(size_t)b * AGW + AA + e + 256];
    xcat[(size_t)b * XC + EM + e]       = s0 * sigmoidf_(g0);
    xcat[(size_t)b * XC + EM + e + 256] = s1 * sigmoidf_(g1);
}

// ---------------- LSTM: reduce 12 zpart slices + gates; h -> xcat h-slot ----------------
__global__ __launch_bounds__(256) void k_lstm(const float* __restrict__ zpart,
                                              const float* __restrict__ blstm,
                                              float* __restrict__ c,
                                              float* __restrict__ xcat) {
    int i = blockIdx.x * 256 + threadIdx.x;   // 32768
    int b = i >> 9, d = i & (D - 1);
    const float* zp = zpart + (size_t)b * (4 * D);
    float zi = blstm[d], zf = blstm[D + d], zg = blstm[2 * D + d], zo = blstm[3 * D + d];
#pragma unroll
    for (int s = 0; s < ZS1 + ZS2; ++s) {
        const float* p = zp + (size_t)s * B * 4 * D;
        zi += p[d]; zf += p[D + d]; zg += p[2 * D + d]; zo += p[3 * D + d];
    }
    float iv = sigmoidf_(zi), fv = sigmoidf_(zf), gv = tanhf(zg), ov = sigmoidf_(zo);
    float cn = fv * c[i] + iv * gv;
    c[i] = cn;
    xcat[(size_t)b * XC + HOFF + d] = ov * tanhf(cn);
}

// ---------------- argmax over V -> token + next inp into xcat ----------------
__global__ __launch_bounds__(256) void k_argmax(const float* __restrict__ preds,
                                                const float* __restrict__ emb,
                                                float* __restrict__ xcat,
                                                int* __restrict__ out,
                                                int step) {
    __shared__ float vals[256];
    __shared__ int idxs[256];
    __shared__ int pid_sh;
    int b = blockIdx.x, t = threadIdx.x;
    const float* p = preds + (size_t)b * V;
    float best = -INFINITY; int bi = 0;
    for (int v = t; v < V; v += 256) {
        float pv = p[v];
        if (pv > best) { best = pv; bi = v; }
    }
    vals[t] = best; idxs[t] = bi; __syncthreads();
    for (int s = 128; s; s >>= 1) {
        if (t < s) {
            float ov = vals[t + s]; int oi = idxs[t + s];
            if (ov > vals[t] || (ov == vals[t] && oi < idxs[t])) { vals[t] = ov; idxs[t] = oi; }
        }
        __syncthreads();
    }
    if (t == 0) { pid_sh = idxs[0]; out[b * TSTEPS + step] = idxs[0]; }
    __syncthreads();
    int pid = pid_sh;
    for (int k = t; k < EM; k += 256) xcat[(size_t)b * XC + k] = emb[(size_t)pid * EM + k];
}

extern "C" void kernel_launch(void* const* d_in, const int* in_sizes, int n_in,
                              void* d_out, int out_size, void* d_ws, size_t ws_size,
                              hipStream_t stream) {
    const float* feat   = (const float*)d_in[0];
    const float* emb    = (const float*)d_in[1];
    const float* Wea    = (const float*)d_in[2];
    const float* Wda    = (const float*)d_in[3];
    const float* wfull  = (const float*)d_in[4];
    const float* Wih_   = (const float*)d_in[5];
    const float* bih    = (const float*)d_in[6];
    const float* Wic    = (const float*)d_in[7];
    const float* bic    = (const float*)d_in[8];
    const float* Wfb    = (const float*)d_in[9];
    const float* bfb    = (const float*)d_in[10];
    const float* Wih    = (const float*)d_in[11];
    const float* Whh    = (const float*)d_in[12];
    const float* blstm  = (const float*)d_in[13];
    const float* Wfc    = (const float*)d_in[14];
    const float* bfc    = (const float*)d_in[15];
    int* out = (int*)d_out;

    float* ws = (float*)d_ws;
    float* att1     = ws;                              // 6422528
    float* mean_enc = att1 + (size_t)B * N * AA;       // 131072
    float* c        = mean_enc + (size_t)B * E;        // 32768
    float* ag       = c + (size_t)B * D;               // 163840
    float* alpha    = ag + (size_t)B * AGW;            // 12544
    float* xcat     = alpha + (size_t)B * N;           // 196608
    float* zpart    = xcat + (size_t)B * XC;           // 12*131072 = 1572864
    float* preds    = zpart + (size_t)(ZS1 + ZS2) * B * 4 * D;  // 640000
    // total ~36.7 MB

    // ---- one-time (per call) ----
    k_mean<<<(B * E) / 256, 256, 0, stream>>>(feat, mean_enc);
    k_init_hc<<<(B * D) / 256, 256, 0, stream>>>(mean_enc, Wih_, bih, Wic, bic, xcat, c);
    k_init_inp<<<(B * EM) / 256, 256, 0, stream>>>(emb, xcat);
    k_gemm_att1<<<dim3((B * N) / 128, AA / 64), 256, 0, stream>>>(feat, Wea, att1);

    for (int t = 0; t < TSTEPS; ++t) {
        // att2 = h @ Wda ; gate = h @ Wfb + bfb  (both into ag rows)
        k_gemm64<0><<<dim3(AA / 64, 1), 256, 0, stream>>>(xcat + HOFF, XC, Wda, AA,
                                                          ag, AGW, 0, nullptr, AA, D);
        k_gemm64<0><<<dim3(E / 64, 1), 256, 0, stream>>>(xcat + HOFF, XC, Wfb, E,
                                                         ag + AA, AGW, 0, bfb, E, D);
        k_scores_softmax<<<B, 256, 0, stream>>>(att1, ag, wfull, alpha);
        k_awe<<<dim3(4, B), 256, 0, stream>>>(alpha, feat, ag, xcat);
        // z partials: [inp|awe] @ W_ih  (8 slices, K=2560), h @ W_hh (4 slices, K=512)
        k_gemm64<0><<<dim3((4 * D) / 64, ZS1), 256, 0, stream>>>(xcat, XC, Wih, 4 * D,
                                                                 zpart, 4 * D, (size_t)B * 4 * D,
                                                                 nullptr, 4 * D, (EM + E) / ZS1);
        k_gemm64<0><<<dim3((4 * D) / 64, ZS2), 256, 0, stream>>>(xcat + HOFF, XC, Whh, 4 * D,
                                                                 zpart + (size_t)ZS1 * B * 4 * D, 4 * D,
                                                                 (size_t)B * 4 * D,
                                                                 nullptr, 4 * D, D / ZS2);
        k_lstm<<<(B * D) / 256, 256, 0, stream>>>(zpart, blstm, c, xcat);
        k_gemm64<1><<<dim3((V + 63) / 64, 1), 256, 0, stream>>>(xcat + HOFF, XC, Wfc, V,
                                                                preds, V, 0, bfc, V, D);
        k_argmax<<<B, 256, 0, stream>>>(preds, emb, xcat, out, t);
    }
}

// Round 4
// 3158.687 us; speedup vs baseline: 1.9625x; 1.3932x over previous
//
#include <hip/hip_runtime.h>
#include <math.h>

#define B 64
#define N 196
#define E 2048
#define D 512
#define AA 512
#define EM 512
#define V 10000
#define TSTEPS 20
#define XC 3072          // xcat: [inp(512) | awe(2048) | h(512)] contiguous
#define HOFF 2560        // h slot offset in xcat
#define AGW 2560         // ag row: [att2(512) | gate(2048)]
#define ZS1 8            // split-K slices for W_ih (K=2560 -> 320 each)
#define ZS2 4            // split-K slices for W_hh (K=512 -> 128 each)

__device__ __forceinline__ float sigmoidf_(float x) { return 1.0f / (1.0f + expf(-x)); }

// ---------------- mean over N ----------------
__global__ __launch_bounds__(256) void k_mean(const float* __restrict__ feat,
                                              float* __restrict__ mean_enc) {
    int i = blockIdx.x * 256 + threadIdx.x;
    int b = i >> 11, e = i & (E - 1);
    const float* p = feat + (size_t)b * N * E + e;
    float s = 0.f;
    for (int n = 0; n < N; ++n) s += p[(size_t)n * E];
    mean_enc[i] = s * (1.0f / (float)N);
}

// ---------------- h,c init; h written into xcat h-slot ----------------
__global__ __launch_bounds__(256) void k_init_hc(const float* __restrict__ me,
                                                 const float* __restrict__ Wh, const float* __restrict__ bh,
                                                 const float* __restrict__ Wc, const float* __restrict__ bc,
                                                 float* __restrict__ xcat, float* __restrict__ c) {
    int i = blockIdx.x * 256 + threadIdx.x;
    int b = i >> 9, d = i & (D - 1);
    const float* m = me + (size_t)b * E;
    float ha = bh[d], ca = bc[d];
    for (int e = 0; e < E; ++e) {
        float mv = m[e];
        ha += mv * Wh[(size_t)e * D + d];
        ca += mv * Wc[(size_t)e * D + d];
    }
    xcat[(size_t)b * XC + HOFF + d] = ha;
    c[i] = ca;
}

// ---------------- inp = embedding[1] into xcat ----------------
__global__ __launch_bounds__(256) void k_init_inp(const float* __restrict__ emb,
                                                  float* __restrict__ xcat) {
    int i = blockIdx.x * 256 + threadIdx.x;   // 32768
    int b = i >> 9, k = i & (EM - 1);
    xcat[(size_t)b * XC + k] = emb[EM + k];
}

// ---------------- att1 = enc @ W_enc_att : 128x128 tile, BK=16, 8x8 micro ----------------
// LDS budget: per kk, 4 b128-reads per 64 FMA -> LDS demand = peak (128B/cyc), near-conflict-free.
// XCD-chunked swizzle: 392 blocks = 8 x 49, col-tiles sharing an A row-tile land on one XCD's L2.
__global__ __launch_bounds__(256) void k_gemm_att1(const float* __restrict__ Am,
                                                   const float* __restrict__ Bm,
                                                   float* __restrict__ Cm) {
    __shared__ float As[16][128];   // [k][m]
    __shared__ float Bs[16][128];   // [k][n]
    int bid = blockIdx.x;           // 392 = 98 row-tiles x 4 col-tiles
    int swz = (bid & 7) * 49 + (bid >> 3);    // bijective: 392 % 8 == 0
    int row0 = (swz >> 2) * 128, col0 = (swz & 3) * 128;
    int t = threadIdx.x;
    int lrow = t >> 1, lk8 = (t & 1) * 8;     // A staging: 2 x float4 per thread
    int bk = t >> 4, bc8 = (t & 15) * 8;      // B staging: 2 x float4 per thread
    int ty = t >> 4, tx = t & 15;
    float acc[8][8] = {};
    for (int k0 = 0; k0 < E; k0 += 16) {
        const float* ap = &Am[(size_t)(row0 + lrow) * E + k0 + lk8];
        float4 a0 = *(const float4*)ap;
        float4 a1 = *(const float4*)(ap + 4);
        As[lk8 + 0][lrow] = a0.x; As[lk8 + 1][lrow] = a0.y;
        As[lk8 + 2][lrow] = a0.z; As[lk8 + 3][lrow] = a0.w;
        As[lk8 + 4][lrow] = a1.x; As[lk8 + 5][lrow] = a1.y;
        As[lk8 + 6][lrow] = a1.z; As[lk8 + 7][lrow] = a1.w;
        const float* bp = &Bm[(size_t)(k0 + bk) * AA + col0 + bc8];
        *(float4*)&Bs[bk][bc8]     = *(const float4*)bp;
        *(float4*)&Bs[bk][bc8 + 4] = *(const float4*)(bp + 4);
        __syncthreads();
#pragma unroll
        for (int kk = 0; kk < 16; ++kk) {
            float4 aL = *(const float4*)&As[kk][ty * 4];
            float4 aH = *(const float4*)&As[kk][64 + ty * 4];
            float4 bL = *(const float4*)&Bs[kk][tx * 4];
            float4 bH = *(const float4*)&Bs[kk][64 + tx * 4];
            float av[8] = {aL.x, aL.y, aL.z, aL.w, aH.x, aH.y, aH.z, aH.w};
            float bv[8] = {bL.x, bL.y, bL.z, bL.w, bH.x, bH.y, bH.z, bH.w};
#pragma unroll
            for (int i = 0; i < 8; ++i)
#pragma unroll
                for (int j = 0; j < 8; ++j)
                    acc[i][j] += av[i] * bv[j];
        }
        __syncthreads();
    }
#pragma unroll
    for (int i = 0; i < 8; ++i) {
        int row = row0 + ((i < 4) ? (ty * 4 + i) : (64 + ty * 4 + i - 4));
        float4 lo, hi;
        lo.x = acc[i][0]; lo.y = acc[i][1]; lo.z = acc[i][2]; lo.w = acc[i][3];
        hi.x = acc[i][4]; hi.y = acc[i][5]; hi.z = acc[i][6]; hi.w = acc[i][7];
        *(float4*)&Cm[(size_t)row * AA + col0 + tx * 4]      = lo;
        *(float4*)&Cm[(size_t)row * AA + col0 + 64 + tx * 4] = hi;
    }
}

// ---------------- fused att2|gate: ag[b] = [h@Wda | h@Wfb + bfb] ----------------
__global__ __launch_bounds__(256) void k_ag(const float* __restrict__ xcat,
                                            const float* __restrict__ Wda,
                                            const float* __restrict__ Wfb,
                                            const float* __restrict__ bfb,
                                            float* __restrict__ ag) {
    __shared__ float As[16][68];
    __shared__ float Bs[16][64];
    int tile = blockIdx.x;          // 0..39: 0-7 att2, 8-39 gate
    const float* W; const float* bias; int ldw, n0, co;
    if (tile < 8) { W = Wda; ldw = AA; n0 = tile * 64;       co = n0;       bias = nullptr; }
    else          { W = Wfb; ldw = E;  n0 = (tile - 8) * 64; co = AA + n0;  bias = bfb; }
    const float* A = xcat + HOFF;   // h, row stride XC
    int t = threadIdx.x;
    int tx = t & 15, ty = t >> 4;
    int arow = t >> 2, ak4 = (t & 3) * 4;
    int bk = t >> 4, bc4 = (t & 15) * 4;
    float acc[4][4] = {};
    for (int k0 = 0; k0 < D; k0 += 16) {
        float4 av = *(const float4*)&A[(size_t)arow * XC + k0 + ak4];
        As[ak4 + 0][arow] = av.x; As[ak4 + 1][arow] = av.y;
        As[ak4 + 2][arow] = av.z; As[ak4 + 3][arow] = av.w;
        *(float4*)&Bs[bk][bc4] = *(const float4*)&W[(size_t)(k0 + bk) * ldw + n0 + bc4];
        __syncthreads();
#pragma unroll
        for (int kk = 0; kk < 16; ++kk) {
            float4 a4 = *(const float4*)&As[kk][ty * 4];
            float4 b4 = *(const float4*)&Bs[kk][tx * 4];
            acc[0][0] += a4.x * b4.x; acc[0][1] += a4.x * b4.y; acc[0][2] += a4.x * b4.z; acc[0][3] += a4.x * b4.w;
            acc[1][0] += a4.y * b4.x; acc[1][1] += a4.y * b4.y; acc[1][2] += a4.y * b4.z; acc[1][3] += a4.y * b4.w;
            acc[2][0] += a4.z * b4.x; acc[2][1] += a4.z * b4.y; acc[2][2] += a4.z * b4.z; acc[2][3] += a4.z * b4.w;
            acc[3][0] += a4.w * b4.x; acc[3][1] += a4.w * b4.y; acc[3][2] += a4.w * b4.z; acc[3][3] += a4.w * b4.w;
        }
        __syncthreads();
    }
#pragma unroll
    for (int i = 0; i < 4; ++i) {
        int row = ty * 4 + i;
#pragma unroll
        for (int j = 0; j < 4; ++j) {
            float v = acc[i][j];
            if (bias) v += bias[n0 + tx * 4 + j];
            ag[(size_t)row * AGW + co + tx * 4 + j] = v;
        }
    }
}

// ---------------- scores: wave per (b,n) row ----------------
__global__ __launch_bounds__(256) void k_scores(const float* __restrict__ att1,
                                                const float* __restrict__ ag,
                                                const float* __restrict__ wfull,
                                                float* __restrict__ scores) {
    int wid = threadIdx.x >> 6, lane = threadIdx.x & 63;
    int bn = blockIdx.x * 4 + wid;            // 12544 rows
    int b = bn / N;
    const float* a1 = att1 + (size_t)bn * AA;
    const float* a2 = ag + (size_t)b * AGW;
    float s = 0.f;
#pragma unroll
    for (int i = 0; i < AA / 64; ++i) {
        int a = lane + i * 64;
        s += fmaxf(a1[a] + a2[a], 0.f) * wfull[a];
    }
    for (int off = 32; off; off >>= 1) s += __shfl_down(s, off);
    if (lane == 0) scores[bn] = s;
}

// ---------------- awe: in-block softmax + weighted sum + gate ----------------
// grid (E/256, B); each block recomputes softmax over 196 scores (trivial), then 256 e's.
__global__ __launch_bounds__(256) void k_awe(const float* __restrict__ scores,
                                             const float* __restrict__ feat,
                                             const float* __restrict__ ag,
                                             float* __restrict__ xcat) {
    __shared__ float al[N];
    __shared__ float red[256];
    int b = blockIdx.y, ch = blockIdx.x, t = threadIdx.x;
    float v = (t < N) ? scores[b * N + t] : -INFINITY;
    red[t] = v; __syncthreads();
    for (int s = 128; s; s >>= 1) { if (t < s) red[t] = fmaxf(red[t], red[t + s]); __syncthreads(); }
    float mx = red[0]; __syncthreads();
    float e = (t < N) ? expf(v - mx) : 0.f;
    red[t] = e; __syncthreads();
    for (int s = 128; s; s >>= 1) { if (t < s) red[t] += red[t + s]; __syncthreads(); }
    float inv = 1.0f / red[0];
    if (t < N) al[t] = e * inv;
    __syncthreads();
    int e0 = ch * 256 + t;
    const float* f = feat + (size_t)b * N * E + e0;
    float s0 = 0.f;
    int n = 0;
    for (; n + 4 <= N; n += 4) {
        s0 += al[n] * f[0];
        s0 += al[n + 1] * f[E];
        s0 += al[n + 2] * f[2 * E];
        s0 += al[n + 3] * f[3 * E];
        f += (size_t)4 * E;
    }
    for (; n < N; ++n) { s0 += al[n] * f[0]; f += E; }
    float g = ag[(size_t)b * AGW + AA + e0];
    xcat[(size_t)b * XC + EM + e0] = s0 * sigmoidf_(g);
}

// ---------------- z partials: one launch, 12 slices (8 ih + 4 hh) ----------------
__global__ __launch_bounds__(256) void k_z(const float* __restrict__ xcat,
                                           const float* __restrict__ Wih,
                                           const float* __restrict__ Whh,
                                           float* __restrict__ zpart) {
    __shared__ float As[16][68];
    __shared__ float Bs[16][64];
    int slice = blockIdx.y;
    const float* A; const float* W; int kbeg, kspan;
    if (slice < ZS1) { A = xcat;        W = Wih; kbeg = slice * ((EM + E) / ZS1); kspan = (EM + E) / ZS1; }
    else             { A = xcat + HOFF; W = Whh; kbeg = (slice - ZS1) * (D / ZS2); kspan = D / ZS2; }
    float* C = zpart + (size_t)slice * B * 4 * D;
    int n0 = blockIdx.x * 64;
    int t = threadIdx.x;
    int tx = t & 15, ty = t >> 4;
    int arow = t >> 2, ak4 = (t & 3) * 4;
    int bk = t >> 4, bc4 = (t & 15) * 4;
    float acc[4][4] = {};
    for (int k0 = kbeg; k0 < kbeg + kspan; k0 += 16) {
        float4 av = *(const float4*)&A[(size_t)arow * XC + k0 + ak4];
        As[ak4 + 0][arow] = av.x; As[ak4 + 1][arow] = av.y;
        As[ak4 + 2][arow] = av.z; As[ak4 + 3][arow] = av.w;
        *(float4*)&Bs[bk][bc4] = *(const float4*)&W[(size_t)(k0 + bk) * (4 * D) + n0 + bc4];
        __syncthreads();
#pragma unroll
        for (int kk = 0; kk < 16; ++kk) {
            float4 a4 = *(const float4*)&As[kk][ty * 4];
            float4 b4 = *(const float4*)&Bs[kk][tx * 4];
            acc[0][0] += a4.x * b4.x; acc[0][1] += a4.x * b4.y; acc[0][2] += a4.x * b4.z; acc[0][3] += a4.x * b4.w;
            acc[1][0] += a4.y * b4.x; acc[1][1] += a4.y * b4.y; acc[1][2] += a4.y * b4.z; acc[1][3] += a4.y * b4.w;
            acc[2][0] += a4.z * b4.x; acc[2][1] += a4.z * b4.y; acc[2][2] += a4.z * b4.z; acc[2][3] += a4.z * b4.w;
            acc[3][0] += a4.w * b4.x; acc[3][1] += a4.w * b4.y; acc[3][2] += a4.w * b4.z; acc[3][3] += a4.w * b4.w;
        }
        __syncthreads();
    }
#pragma unroll
    for (int i = 0; i < 4; ++i) {
        int row = ty * 4 + i;
#pragma unroll
        for (int j = 0; j < 4; ++j)
            C[(size_t)row * (4 * D) + n0 + tx * 4 + j] = acc[i][j];
    }
}

// ---------------- LSTM: reduce 12 zpart slices + gates; h -> xcat h-slot ----------------
__global__ __launch_bounds__(256) void k_lstm(const float* __restrict__ zpart,
                                              const float* __restrict__ blstm,
                                              float* __restrict__ c,
                                              float* __restrict__ xcat) {
    int i = blockIdx.x * 256 + threadIdx.x;   // 32768
    int b = i >> 9, d = i & (D - 1);
    const float* zp = zpart + (size_t)b * (4 * D);
    float zi = blstm[d], zf = blstm[D + d], zg = blstm[2 * D + d], zo = blstm[3 * D + d];
#pragma unroll
    for (int s = 0; s < ZS1 + ZS2; ++s) {
        const float* p = zp + (size_t)s * B * 4 * D;
        zi += p[d]; zf += p[D + d]; zg += p[2 * D + d]; zo += p[3 * D + d];
    }
    float iv = sigmoidf_(zi), fv = sigmoidf_(zf), gv = tanhf(zg), ov = sigmoidf_(zo);
    float cn = fv * c[i] + iv * gv;
    c[i] = cn;
    xcat[(size_t)b * XC + HOFF + d] = ov * tanhf(cn);
}

// ---------------- preds = h @ W_fc + b_fc (guarded N) ----------------
__global__ __launch_bounds__(256) void k_preds(const float* __restrict__ xcat,
                                               const float* __restrict__ Wfc,
                                               const float* __restrict__ bfc,
                                               float* __restrict__ preds) {
    __shared__ float As[16][68];
    __shared__ float Bs[16][64];
    const float* A = xcat + HOFF;
    int n0 = blockIdx.x * 64;
    int t = threadIdx.x;
    int tx = t & 15, ty = t >> 4;
    int arow = t >> 2, ak4 = (t & 3) * 4;
    int bk = t >> 4, bc4 = (t & 15) * 4;
    float acc[4][4] = {};
    for (int k0 = 0; k0 < D; k0 += 16) {
        float4 av = *(const float4*)&A[(size_t)arow * XC + k0 + ak4];
        As[ak4 + 0][arow] = av.x; As[ak4 + 1][arow] = av.y;
        As[ak4 + 2][arow] = av.z; As[ak4 + 3][arow] = av.w;
        int n = n0 + bc4;
        const float* wp = &Wfc[(size_t)(k0 + bk) * V];
        float4 bv;
        if (n + 3 < V) bv = *(const float4*)&wp[n];
        else {
            bv.x = (n     < V) ? wp[n]     : 0.f;
            bv.y = (n + 1 < V) ? wp[n + 1] : 0.f;
            bv.z = (n + 2 < V) ? wp[n + 2] : 0.f;
            bv.w = (n + 3 < V) ? wp[n + 3] : 0.f;
        }
        *(float4*)&Bs[bk][bc4] = bv;
        __syncthreads();
#pragma unroll
        for (int kk = 0; kk < 16; ++kk) {
            float4 a4 = *(const float4*)&As[kk][ty * 4];
            float4 b4 = *(const float4*)&Bs[kk][tx * 4];
            acc[0][0] += a4.x * b4.x; acc[0][1] += a4.x * b4.y; acc[0][2] += a4.x * b4.z; acc[0][3] += a4.x * b4.w;
            acc[1][0] += a4.y * b4.x; acc[1][1] += a4.y * b4.y; acc[1][2] += a4.y * b4.z; acc[1][3] += a4.y * b4.w;
            acc[2][0] += a4.z * b4.x; acc[2][1] += a4.z * b4.y; acc[2][2] += a4.z * b4.z; acc[2][3] += a4.z * b4.w;
            acc[3][0] += a4.w * b4.x; acc[3][1] += a4.w * b4.y; acc[3][2] += a4.w * b4.z; acc[3][3] += a4.w * b4.w;
        }
        __syncthreads();
    }
#pragma unroll
    for (int i = 0; i < 4; ++i) {
        int row = ty * 4 + i;
#pragma unroll
        for (int j = 0; j < 4; ++j) {
            int col = n0 + tx * 4 + j;
            if (col < V) preds[(size_t)row * V + col] = acc[i][j] + bfc[col];
        }
    }
}

// ---------------- argmax over V -> token + next inp into xcat ----------------
__global__ __launch_bounds__(256) void k_argmax(const float* __restrict__ preds,
                                                const float* __restrict__ emb,
                                                float* __restrict__ xcat,
                                                int* __restrict__ out,
                                                int step) {
    __shared__ float vals[256];
    __shared__ int idxs[256];
    __shared__ int pid_sh;
    int b = blockIdx.x, t = threadIdx.x;
    const float* p = preds + (size_t)b * V;
    float best = -INFINITY; int bi = 0;
    for (int v = t; v < V; v += 256) {
        float pv = p[v];
        if (pv > best) { best = pv; bi = v; }
    }
    vals[t] = best; idxs[t] = bi; __syncthreads();
    for (int s = 128; s; s >>= 1) {
        if (t < s) {
            float ov = vals[t + s]; int oi = idxs[t + s];
            if (ov > vals[t] || (ov == vals[t] && oi < idxs[t])) { vals[t] = ov; idxs[t] = oi; }
        }
        __syncthreads();
    }
    if (t == 0) { pid_sh = idxs[0]; out[b * TSTEPS + step] = idxs[0]; }
    __syncthreads();
    int pid = pid_sh;
    for (int k = t; k < EM; k += 256) xcat[(size_t)b * XC + k] = emb[(size_t)pid * EM + k];
}

extern "C" void kernel_launch(void* const* d_in, const int* in_sizes, int n_in,
                              void* d_out, int out_size, void* d_ws, size_t ws_size,
                              hipStream_t stream) {
    const float* feat   = (const float*)d_in[0];
    const float* emb    = (const float*)d_in[1];
    const float* Wea    = (const float*)d_in[2];
    const float* Wda    = (const float*)d_in[3];
    const float* wfull  = (const float*)d_in[4];
    const float* Wih_   = (const float*)d_in[5];
    const float* bih    = (const float*)d_in[6];
    const float* Wic    = (const float*)d_in[7];
    const float* bic    = (const float*)d_in[8];
    const float* Wfb    = (const float*)d_in[9];
    const float* bfb    = (const float*)d_in[10];
    const float* Wih    = (const float*)d_in[11];
    const float* Whh    = (const float*)d_in[12];
    const float* blstm  = (const float*)d_in[13];
    const float* Wfc    = (const float*)d_in[14];
    const float* bfc    = (const float*)d_in[15];
    int* out = (int*)d_out;

    float* ws = (float*)d_ws;
    float* att1     = ws;                              // 6422528
    float* mean_enc = att1 + (size_t)B * N * AA;       // 131072
    float* c        = mean_enc + (size_t)B * E;        // 32768
    float* ag       = c + (size_t)B * D;               // 163840
    float* scores   = ag + (size_t)B * AGW;            // 12544
    float* xcat     = scores + (size_t)B * N;          // 196608
    float* zpart    = xcat + (size_t)B * XC;           // 1572864
    float* preds    = zpart + (size_t)(ZS1 + ZS2) * B * 4 * D;  // 640000

    // ---- one-time (per call) ----
    k_mean<<<(B * E) / 256, 256, 0, stream>>>(feat, mean_enc);
    k_init_hc<<<(B * D) / 256, 256, 0, stream>>>(mean_enc, Wih_, bih, Wic, bic, xcat, c);
    k_init_inp<<<(B * EM) / 256, 256, 0, stream>>>(emb, xcat);
    k_gemm_att1<<<(B * N / 128) * (AA / 128), 256, 0, stream>>>(feat, Wea, att1);

    for (int t = 0; t < TSTEPS; ++t) {
        k_ag<<<40, 256, 0, stream>>>(xcat, Wda, Wfb, bfb, ag);
        k_scores<<<(B * N) / 4, 256, 0, stream>>>(att1, ag, wfull, scores);
        k_awe<<<dim3(E / 256, B), 256, 0, stream>>>(scores, feat, ag, xcat);
        k_z<<<dim3((4 * D) / 64, ZS1 + ZS2), 256, 0, stream>>>(xcat, Wih, Whh, zpart);
        k_lstm<<<(B * D) / 256, 256, 0, stream>>>(zpart, blstm, c, xcat);
        k_preds<<<(V + 63) / 64, 256, 0, stream>>>(xcat, Wfc, bfc, preds);
        k_argmax<<<B, 256, 0, stream>>>(preds, emb, xcat, out, t);
    }
}